// Round 4
// baseline (211.284 us; speedup 1.0000x reference)
//
#include <hip/hip_runtime.h>
#include <math.h>

#define IMG_H 512
#define IMG_W 512
#define IMG_HW (IMG_H * IMG_W)

namespace {

// float32-rounded cos(k*pi/16) values
constexpr float CFv[9] = {
    1.0f,
    0.98078528040323044913f,
    0.92387953251128675613f,
    0.83146961230254523708f,
    0.70710678118654752440f,
    0.55557023301960222474f,
    0.38268343236508977173f,
    0.19509032201612826785f,
    0.0f
};

struct CTab {
    float  cf[8][8];     // C[x][u] = f32(cos((2x+1)u pi/16))
    double cd[8][8];     // promoted to double
    float  aof[8][8];    // ALPHA outer product (f32)
    float  scalef[8][8]; // DCT_SCALE = ALPHA*0.25
};

constexpr CTab make_ctab() {
    CTab t{};
    for (int y = 0; y < 8; y++) {
        for (int v = 0; v < 8; v++) {
            int a = ((2 * y + 1) * v) & 31;
            if (a > 16) a = 32 - a;
            float val = (a <= 8) ? CFv[a] : -CFv[16 - a];
            t.cf[y][v] = val;
            t.cd[y][v] = (double)val;
        }
    }
    constexpr float A0 = 0.70710678118654752440f;
    for (int u = 0; u < 8; u++) {
        for (int v = 0; v < 8; v++) {
            float au = (u == 0) ? A0 : 1.0f;
            float av = (v == 0) ? A0 : 1.0f;
            float ao = au * av;
            t.aof[u][v] = ao;
            t.scalef[u][v] = ao * 0.25f;
        }
    }
    return t;
}

constexpr CTab CT = make_ctab();

// color coefficients: f32-rounded, promoted to double, 255 folded in
constexpr double YC0 = (double)0.299f     * 255.0;
constexpr double YC1 = (double)0.587f     * 255.0;
constexpr double YC2 = (double)0.114f     * 255.0;
constexpr double CB0 = (double)-0.168736f * 255.0;
constexpr double CB1 = (double)-0.331264f * 255.0;
constexpr double CB2 = (double)0.5f       * 255.0;
constexpr double CR0 = (double)0.5f       * 255.0;
constexpr double CR1 = (double)-0.418688f * 255.0;
constexpr double CR2 = (double)-0.081312f * 255.0;

// ---- LDS layout (bytes), tile = 128x16 -------------------------------------
// lY   double[16*130] @0      16640  (Y-128, stride 130 doubles)
//   overlay after B2: yR f32[16*132]@0 (8448), cbR f32[8*66]@8448 (2112), crR f32[8*66]@10560
// cbP  double[8*66]   @16640  4224   (centered pooled chroma, 64 wide)
// crP  double[8*66]   @20864  4224
// qY   double[144]    @25088  1152   ([v*18+2u]=fs, +1=ds)
// qC   double[144]    @26240  1152
#define OFF_CBP 16640
#define OFF_CRP 20864
#define OFF_QY  25088
#define OFF_QC  26240
#define SMEM_BYTES 27392
#define OFF_CBR 8448
#define OFF_CRR 10560

__device__ __forceinline__ void xpose8_d(double v[8]) {
    const int l = threadIdx.x & 7;
    #pragma unroll
    for (int m = 1; m < 8; m <<= 1) {
        #pragma unroll
        for (int k = 0; k < 8; k++) {
            if ((k & m) == 0) {
                const int kp = k | m;
                double send = (l & m) ? v[k] : v[kp];
                double recv = __shfl_xor(send, m);
                v[k]  = (l & m) ? recv : v[k];
                v[kp] = (l & m) ? v[kp] : recv;
            }
        }
    }
}

__device__ __forceinline__ void xpose8_f(float v[8]) {
    const int l = threadIdx.x & 7;
    #pragma unroll
    for (int m = 1; m < 8; m <<= 1) {
        #pragma unroll
        for (int k = 0; k < 8; k++) {
            if ((k & m) == 0) {
                const int kp = k | m;
                float send = (l & m) ? v[k] : v[kp];
                float recv = __shfl_xor(send, m);
                v[k]  = (l & m) ? recv : v[k];
                v[kp] = (l & m) ? v[kp] : recv;
            }
        }
    }
}

// forward 8-pt pass with even/odd symmetry (fp64), input already centered
__device__ __forceinline__ void fdct8_d(const double a[8], double s[8]) {
    double e[4], o[4];
    #pragma unroll
    for (int i = 0; i < 4; i++) { e[i] = a[i] + a[7 - i]; o[i] = a[i] - a[7 - i]; }
    #pragma unroll
    for (int v = 0; v < 8; v += 2) {
        s[v]     = e[0] * CT.cd[0][v]     + e[1] * CT.cd[1][v]     + e[2] * CT.cd[2][v]     + e[3] * CT.cd[3][v];
        s[v + 1] = o[0] * CT.cd[0][v + 1] + o[1] * CT.cd[1][v + 1] + o[2] * CT.cd[2][v + 1] + o[3] * CT.cd[3][v + 1];
    }
}

// col pass + quant + diff_round + dequant + IDCT over u  (lane holds column r)
__device__ __forceinline__ void quant_idct_u(const double s1[8], const double* qtab, int r, float m[8]) {
    double e[4], o[4];
    #pragma unroll
    for (int i = 0; i < 4; i++) { e[i] = s1[i] + s1[7 - i]; o[i] = s1[i] - s1[7 - i]; }
    double D[8];
    #pragma unroll
    for (int u = 0; u < 8; u += 2) {
        D[u]     = e[0] * CT.cd[0][u]     + e[1] * CT.cd[1][u]     + e[2] * CT.cd[2][u]     + e[3] * CT.cd[3][u];
        D[u + 1] = o[0] * CT.cd[0][u + 1] + o[1] * CT.cd[1][u + 1] + o[2] * CT.cd[2][u + 1] + o[3] * CT.cd[3][u + 1];
    }
    float dq[8];
    #pragma unroll
    for (int u = 0; u < 8; u++) {
        double2 q = *(const double2*)&qtab[r * 18 + 2 * u];  // {fs, ds}
        double xq = D[u] * q.x;
        double rq = rint(xq);
        double ee = xq - rq;
        dq[u] = (float)((rq + ee * ee * ee) * q.y);
    }
    #pragma unroll
    for (int x = 0; x < 4; x++) {
        float E = dq[0] * CT.cf[x][0] + dq[2] * CT.cf[x][2] + dq[4] * CT.cf[x][4] + dq[6] * CT.cf[x][6];
        float O = dq[1] * CT.cf[x][1] + dq[3] * CT.cf[x][3] + dq[5] * CT.cf[x][5] + dq[7] * CT.cf[x][7];
        m[x]     = E + O;
        m[7 - x] = E - O;
    }
}

// IDCT over v (fp32), write spatial row (8 contiguous floats)
__device__ __forceinline__ void idct_v_store(const float m[8], float* dst, float addv) {
    #pragma unroll
    for (int y = 0; y < 4; y++) {
        float E = m[0] * CT.cf[y][0] + m[2] * CT.cf[y][2] + m[4] * CT.cf[y][4] + m[6] * CT.cf[y][6];
        float O = m[1] * CT.cf[y][1] + m[3] * CT.cf[y][3] + m[5] * CT.cf[y][5] + m[7] * CT.cf[y][7];
        dst[y]     = 0.25f * (E + O) + addv;
        dst[7 - y] = 0.25f * (E - O) + addv;
    }
}

} // namespace

__global__ void __launch_bounds__(256, 4) djpeg_kernel(
    const float* __restrict__ img,
    const float* __restrict__ ytab,
    const float* __restrict__ ctab,
    float* __restrict__ out)
{
    __shared__ __align__(16) unsigned char smem[SMEM_BYTES];
    double* lY  = (double*)(smem);
    double* cbP = (double*)(smem + OFF_CBP);
    double* crP = (double*)(smem + OFF_CRP);
    double* qY  = (double*)(smem + OFF_QY);
    double* qC  = (double*)(smem + OFF_QC);
    float* yR  = (float*)(smem);            // stride 132 floats
    float* cbR = (float*)(smem + OFF_CBR);  // stride 66
    float* crR = (float*)(smem + OFF_CRR);

    const int t  = threadIdx.x;
    const int X0 = blockIdx.x * 128;
    const int Y0 = blockIdx.y * 16;
    const int bi = blockIdx.z;

    // ---- quant factors (fp64; table*0.4 in f32 per weak-scalar promotion)
    if (t < 128) {
        const float* tab = (t < 64) ? ytab : ctab;
        double* q = (t < 64) ? qY : qC;
        int e = t & 63, u = e >> 3, v = e & 7;
        float tfacf = tab[e] * 0.4f;
        double tf = (double)tfacf;
        q[v * 18 + 2 * u]     = (double)CT.scalef[u][v] / tf;  // fs
        q[v * 18 + 2 * u + 1] = tf * (double)CT.aof[u][v];     // ds (includes ALPHA)
    }

    // ---- phase 1: float4 loads, centered YCbCr (fp64), Y-128 -> LDS, pooled chroma -> LDS
    {
        const int xg = t & 31, row0 = t >> 5;     // 4*xg = x offset, 8 rows/pass
        size_t base = ((size_t)bi * 3) * IMG_HW + (size_t)Y0 * IMG_W + X0 + 4 * xg;
        #pragma unroll
        for (int i = 0; i < 2; i++) {
            int y = row0 + 8 * i;
            size_t p = base + (size_t)y * IMG_W;
            const float4 Rv = *(const float4*)(img + p);
            const float4 Gv = *(const float4*)(img + p + IMG_HW);
            const float4 Bv = *(const float4*)(img + p + 2 * IMG_HW);
            const float rr[4] = {Rv.x, Rv.y, Rv.z, Rv.w};
            const float gg[4] = {Gv.x, Gv.y, Gv.z, Gv.w};
            const float bb[4] = {Bv.x, Bv.y, Bv.z, Bv.w};
            double Yd[4], Cbv[4], Crv[4];
            #pragma unroll
            for (int k = 0; k < 4; k++) {
                double R = (double)rr[k], G = (double)gg[k], B = (double)bb[k];
                Yd[k]  = YC0 * R + YC1 * G + YC2 * B - 128.0;
                Cbv[k] = CB0 * R + CB1 * G + CB2 * B;
                Crv[k] = CR0 * R + CR1 * G + CR2 * B;
            }
            double2* w = (double2*)&lY[y * 130 + 4 * xg];
            w[0] = make_double2(Yd[0], Yd[1]);
            w[1] = make_double2(Yd[2], Yd[3]);
            double cb01 = Cbv[0] + Cbv[1], cb23 = Cbv[2] + Cbv[3];
            double cr01 = Crv[0] + Crv[1], cr23 = Crv[2] + Crv[3];
            cb01 += __shfl_xor(cb01, 32);
            cb23 += __shfl_xor(cb23, 32);
            cr01 += __shfl_xor(cr01, 32);
            cr23 += __shfl_xor(cr23, 32);
            if ((t & 32) == 0) {
                int yh = y >> 1;
                *(double2*)&cbP[yh * 66 + 2 * xg] = make_double2(cb01 * 0.25, cb23 * 0.25);
                *(double2*)&crP[yh * 66 + 2 * xg] = make_double2(cr01 * 0.25, cr23 * 0.25);
            }
        }
    }
    __syncthreads();  // B1

    // ---- DCT: 48 blocks (32 Y + 8 Cb + 8 Cr), lanes t<192 run TWO independent streams
    const bool act = (t < 192);
    const int r = t & 7;
    const int g0 = t >> 3;                 // 0..23, all Y blocks
    const double* src0 = lY;  const double* src1 = lY;
    const double* qt1 = qY;
    float* dst0 = yR;  float* dst1 = yR;
    float addv1 = 128.0f;
    if (act) {
        // stream 0: Y blocks 0..23 (by=g0>>4 via split below)
        {
            int by = (g0 >> 4), bx = g0 & 15;         // g0<16: by0 bx0..15 ; 16..23: by1 bx0..7
            src0 = lY + (by * 8 + r) * 130 + bx * 8;
            dst0 = yR + (by * 8 + r) * 132 + bx * 8;
        }
        // stream 1: blocks 24..47
        int g1 = g0 + 24;
        if (g1 < 32) {                                // Y, by=1, bx=8..15  (t<64)
            int bx = g1 - 16;
            src1 = lY + (8 + r) * 130 + bx * 8;
            dst1 = yR + (8 + r) * 132 + bx * 8;
            qt1 = qY; addv1 = 128.0f;
        } else if (g1 < 40) {                         // Cb  (64<=t<128)
            int bx = g1 - 32;
            src1 = cbP + r * 66 + bx * 8;
            dst1 = cbR + r * 66 + bx * 8;
            qt1 = qC; addv1 = 0.0f;
        } else {                                      // Cr  (128<=t<192)
            int bx = g1 - 40;
            src1 = crP + r * 66 + bx * 8;
            dst1 = crR + r * 66 + bx * 8;
            qt1 = qC; addv1 = 0.0f;
        }
    }

    double s1a[8], s1b[8];
    if (act) {
        double a[8], b[8];
        #pragma unroll
        for (int y = 0; y < 8; y++) { a[y] = src0[y]; b[y] = src1[y]; }
        fdct8_d(a, s1a);
        fdct8_d(b, s1b);
        xpose8_d(s1a);
        xpose8_d(s1b);
    }
    float ma[8], mb[8];
    if (act) {
        quant_idct_u(s1a, qY, r, ma);
        quant_idct_u(s1b, qt1, r, mb);
        xpose8_f(ma);
        xpose8_f(mb);
    }
    __syncthreads();  // B2: all staging reads done; fp32 overlay becomes writable

    if (act) {
        idct_v_store(ma, dst0, 128.0f);
        idct_v_store(mb, dst1, addv1);
    }
    __syncthreads();  // B3

    // ---- phase 3: upsample chroma (centered), YCbCr->RGB, clip, /255, float4 stores
    {
        const int xg = t & 31, row0 = t >> 5;
        size_t base = ((size_t)bi * 3) * IMG_HW + (size_t)Y0 * IMG_W + X0 + 4 * xg;
        #pragma unroll
        for (int i = 0; i < 2; i++) {
            int y = row0 + 8 * i;
            float4 yv = *(const float4*)&yR[y * 132 + 4 * xg];
            int yh = y >> 1;
            float2 cbv = *(const float2*)&cbR[yh * 66 + 2 * xg];
            float2 crv = *(const float2*)&crR[yh * 66 + 2 * xg];
            const float ya[4] = {yv.x, yv.y, yv.z, yv.w};
            float ro[4], go[4], bo[4];
            #pragma unroll
            for (int k = 0; k < 4; k++) {
                float Cb = (k < 2) ? cbv.x : cbv.y;
                float Cr = (k < 2) ? crv.x : crv.y;
                float Yv = ya[k];
                float Rr = fmaf(1.402f, Cr, Yv);
                float Gg = Yv - 0.344136f * Cb - 0.714136f * Cr;
                float Bb = fmaf(1.772f, Cb, Yv);
                ro[k] = fminf(fmaxf(Rr, 0.0f), 255.0f) * (1.0f / 255.0f);
                go[k] = fminf(fmaxf(Gg, 0.0f), 255.0f) * (1.0f / 255.0f);
                bo[k] = fminf(fmaxf(Bb, 0.0f), 255.0f) * (1.0f / 255.0f);
            }
            size_t p = base + (size_t)y * IMG_W;
            *(float4*)(out + p)              = make_float4(ro[0], ro[1], ro[2], ro[3]);
            *(float4*)(out + p + IMG_HW)     = make_float4(go[0], go[1], go[2], go[3]);
            *(float4*)(out + p + 2 * IMG_HW) = make_float4(bo[0], bo[1], bo[2], bo[3]);
        }
    }
}

extern "C" void kernel_launch(void* const* d_in, const int* in_sizes, int n_in,
                              void* d_out, int out_size, void* d_ws, size_t ws_size,
                              hipStream_t stream) {
    (void)n_in; (void)out_size; (void)d_ws; (void)ws_size;
    const float* img = (const float*)d_in[0];
    const float* yt  = (const float*)d_in[1];
    const float* ct  = (const float*)d_in[2];
    float* out = (float*)d_out;
    int B = in_sizes[0] / (3 * IMG_HW);    // 32
    dim3 grid(IMG_W / 128, IMG_H / 16, B); // (4, 32, 32)
    djpeg_kernel<<<grid, dim3(256, 1, 1), 0, stream>>>(img, yt, ct, out);
}